// Round 9
// baseline (552.057 us; speedup 1.0000x reference)
//
#include <hip/hip_runtime.h>

#define NA 100000
#define NB 100000
#define NEDGE 1600000
#define HD 128
#define OUTD 16
#define NG 256
#define DA 64
#define DB 32
#define PG 8

#define BIN_SHIFT 9
#define BIN_W 512
#define NBINS_R 196              // ceil(100000/512)
#define NBINS 588                // 3 relations
#define PADBIN 10240             // padded slot per bin
#define EPB 8192                 // edges per block in part
#define ECHUNKS 196              // ceil(NEDGE/EPB)

typedef unsigned int uint_t;
typedef unsigned short ushort_t;
typedef unsigned char uchar_t;
typedef __bf16 bf16_t;
typedef bf16_t bf16x8 __attribute__((ext_vector_type(8)));
typedef float f32x4 __attribute__((ext_vector_type(4)));
typedef float f32x2 __attribute__((ext_vector_type(2)));

__device__ __forceinline__ float bflo(uint_t u) {
    union { uint_t i; float f; } c; c.i = u << 16; return c.f;
}
__device__ __forceinline__ float bfhi(uint_t u) {
    union { uint_t i; float f; } c; c.i = u & 0xffff0000u; return c.f;
}
__device__ __forceinline__ uint_t f2bf(float f) {
    union { float f; uint_t i; } c; c.f = f;
    uint_t r = c.i + 0x7FFFu + ((c.i >> 16) & 1u);
    return r >> 16;
}
__device__ __forceinline__ uint_t pack2bf(float lo, float hi) {
    return f2bf(lo) | (f2bf(hi) << 16);
}

// ---------------- weight prep (FRAGMENT-MAJOR layouts) + bias_pa + gcount ---------
// B-fragment for mfma_f32_16x16x32_bf16: lane l holds W[k = kk*32 + (l>>4)*8 + j][col = ni*16 + (l&15)]
// fragment-major: dst[m][ (kk*8+ni)*64 + l ][8]  -> wave load = 1KB contiguous
// blocks 0..39: 5 GEMM matrices; 40..43: Wemb_a (K=64); 44..45: Wemb_b (K=32);
// 46: bias_pa; 47/48: gcount a/b
__global__ void __launch_bounds__(256)
prep_misc_kernel(const float* __restrict__ Wl_ab, const float* __restrict__ Wr_ab,
                 const float* __restrict__ Wl_ba, const float* __restrict__ Wl_aa,
                 const float* __restrict__ Wr_ba, const float* __restrict__ Wr_aa,
                 const float* __restrict__ Wemb_a, const float* __restrict__ Wemb_b,
                 ushort_t* __restrict__ wt_fb, ushort_t* __restrict__ wt_pa,
                 ushort_t* __restrict__ wt_ea, ushort_t* __restrict__ wt_eb,
                 const float* __restrict__ bl_ba, const float* __restrict__ bl_aa,
                 float* __restrict__ bias_pa,
                 const int* __restrict__ batch_a, const int* __restrict__ batch_b,
                 float* __restrict__ ga, float* __restrict__ gb)
{
    const int bx = blockIdx.x;
    __align__(16) ushort_t tmp[8];
    if (bx >= 40) {
        if (bx <= 43) {                          // Wemb_a, K=64, frag-major
            const int id = (bx - 40) * 256 + threadIdx.x;  // 0..1023
            const int kk = id >> 9, ni = (id >> 6) & 7, l = id & 63;
            const int col = ni * 16 + (l & 15);
            const int k0 = kk * 32 + (l >> 4) * 8;
#pragma unroll
            for (int j = 0; j < 8; ++j) tmp[j] = (ushort_t)f2bf(Wemb_a[(k0 + j) * HD + col]);
            *reinterpret_cast<uint4*>(wt_ea + (size_t)id * 8) = *reinterpret_cast<const uint4*>(tmp);
            return;
        }
        if (bx <= 45) {                          // Wemb_b, K=32, frag-major
            const int id = (bx - 44) * 256 + threadIdx.x;  // 0..511
            const int ni = id >> 6, l = id & 63;
            const int col = ni * 16 + (l & 15);
            const int k0 = (l >> 4) * 8;
#pragma unroll
            for (int j = 0; j < 8; ++j) tmp[j] = (ushort_t)f2bf(Wemb_b[(k0 + j) * HD + col]);
            *reinterpret_cast<uint4*>(wt_eb + (size_t)id * 8) = *reinterpret_cast<const uint4*>(tmp);
            return;
        }
        if (bx == 46) {
            if (threadIdx.x < HD) bias_pa[threadIdx.x] = bl_ba[threadIdx.x] + bl_aa[threadIdx.x];
            return;
        }
        // gcount via binary search (batch sorted)
        const int g = threadIdx.x;
        const int* batch = (bx == 48) ? batch_b : batch_a;
        float* outp = (bx == 48) ? gb : ga;
        const int n = NA;
        int lo0 = 0, hi0 = n;
        while (lo0 < hi0) { const int mid = (lo0 + hi0) >> 1; if (batch[mid] < g) lo0 = mid + 1; else hi0 = mid; }
        int lo1 = 0, hi1 = n;
        while (lo1 < hi1) { const int mid = (lo1 + hi1) >> 1; if (batch[mid] < g + 1) lo1 = mid + 1; else hi1 = mid; }
        outp[g] = (float)(lo1 - lo0);
        return;
    }
    const int m = bx >> 3;
    const int id = (bx & 7) * 256 + threadIdx.x;   // 0..2047
    const int kk = id >> 9, ni = (id >> 6) & 7, l = id & 63;
    const int col = ni * 16 + (l & 15);
    const int k0 = kk * 32 + (l >> 4) * 8;
    const float* src = (m == 0) ? Wl_ab : (m == 1) ? Wr_ab : (m == 2) ? Wl_ba
                     : (m == 3) ? Wl_aa : Wr_ba;
#pragma unroll
    for (int j = 0; j < 8; ++j) {
        float v = src[(k0 + j) * HD + col];
        if (m == 4) v += Wr_aa[(k0 + j) * HD + col];
        tmp[j] = (ushort_t)f2bf(v);
    }
    ushort_t* dst = (m < 2) ? (wt_fb + (size_t)m * 16384) : (wt_pa + (size_t)(m - 2) * 16384);
    *reinterpret_cast<uint4*>(dst + (size_t)id * 8) = *reinterpret_cast<const uint4*>(tmp);
}

// ---------------- MFMA input embedding: h = x @ Wemb + b, no LDS, frag-major W ----
template<int K>
__global__ void __launch_bounds__(256)
emb_mfma(const float* __restrict__ x, const ushort_t* __restrict__ wtf,
         const float* __restrict__ bias, ushort_t* __restrict__ h, int n)
{
    constexpr int KST = K / 32;
    const int l = threadIdx.x & 63, w = threadIdx.x >> 6;
    const int lo = l & 15, hi = l >> 4;
    const int row_base = blockIdx.x * 128 + w * 32;

    f32x4 acc[2][8];
    const f32x4 zero = {0.f, 0.f, 0.f, 0.f};
#pragma unroll
    for (int mi = 0; mi < 2; ++mi)
#pragma unroll
        for (int ni = 0; ni < 8; ++ni) acc[mi][ni] = zero;

    bf16x8 a[2][KST];
#pragma unroll
    for (int mi = 0; mi < 2; ++mi) {
        int r = row_base + mi * 16 + lo;
        r = min(r, n - 1);
        const float* xr = x + (size_t)r * K + hi * 8;
#pragma unroll
        for (int kk = 0; kk < KST; ++kk) {
            const float4 f0 = *reinterpret_cast<const float4*>(xr + kk * 32);
            const float4 f1 = *reinterpret_cast<const float4*>(xr + kk * 32 + 4);
            __align__(16) ushort_t us[8];
            us[0] = (ushort_t)f2bf(f0.x); us[1] = (ushort_t)f2bf(f0.y);
            us[2] = (ushort_t)f2bf(f0.z); us[3] = (ushort_t)f2bf(f0.w);
            us[4] = (ushort_t)f2bf(f1.x); us[5] = (ushort_t)f2bf(f1.y);
            us[6] = (ushort_t)f2bf(f1.z); us[7] = (ushort_t)f2bf(f1.w);
            a[mi][kk] = *reinterpret_cast<const bf16x8*>(us);
        }
    }
#pragma unroll
    for (int kk = 0; kk < KST; ++kk) {
#pragma unroll
        for (int ni = 0; ni < 8; ++ni) {
            const bf16x8 b = *reinterpret_cast<const bf16x8*>(wtf + ((size_t)(kk * 8 + ni) * 64 + l) * 8);
            acc[0][ni] = __builtin_amdgcn_mfma_f32_16x16x32_bf16(a[0][kk], b, acc[0][ni], 0, 0, 0);
            acc[1][ni] = __builtin_amdgcn_mfma_f32_16x16x32_bf16(a[1][kk], b, acc[1][ni], 0, 0, 0);
        }
    }
#pragma unroll
    for (int ni = 0; ni < 8; ++ni) {
        const int col = ni * 16 + lo;
        const float bv = bias[col];
#pragma unroll
        for (int mi = 0; mi < 2; ++mi) {
            const f32x4 v = acc[mi][ni];
#pragma unroll
            for (int r = 0; r < 4; ++r) {
                const int row = row_base + mi * 16 + hi * 4 + r;
                if (row < n) h[(size_t)row * HD + col] = (ushort_t)f2bf(v[r] + bv);
            }
        }
    }
}

// ---------------- bf16 -> fp8 e4m3 conversion (coalesced, both tables) ------------
__global__ void __launch_bounds__(256)
conv8_kernel(const ushort_t* __restrict__ h, uchar_t* __restrict__ h8, long n8)
{
    for (long i = (long)blockIdx.x * 256 + threadIdx.x; i < n8; i += (long)gridDim.x * 256) {
        const uint4 v = *reinterpret_cast<const uint4*>(h + i * 8);
        uint_t lo = (uint_t)__builtin_amdgcn_cvt_pk_fp8_f32(bflo(v.x), bfhi(v.x), 0, false);
        lo = (uint_t)__builtin_amdgcn_cvt_pk_fp8_f32(bflo(v.y), bfhi(v.y), lo, true);
        uint_t hi = (uint_t)__builtin_amdgcn_cvt_pk_fp8_f32(bflo(v.z), bfhi(v.z), 0, false);
        hi = (uint_t)__builtin_amdgcn_cvt_pk_fp8_f32(bflo(v.w), bfhi(v.w), hi, true);
        uint2 o; o.x = lo; o.y = hi;
        *reinterpret_cast<uint2*>(h8 + i * 8) = o;
    }
}

// ---------------- partition into PADDED per-bin slots (LDS-staged, coalesced) -----
// packed entry: (dst&511)<<17 | src   (src < 2^17)
__global__ void __launch_bounds__(256)
part3_kernel(const int* __restrict__ ei_ab, const int* __restrict__ ei_ba,
             const int* __restrict__ ei_aa, int* __restrict__ bincnt,
             uint_t* __restrict__ binned)
{
    __shared__ uint_t sorted[EPB];         // 32 KB
    __shared__ int lh[NBINS_R];
    __shared__ int lbase[NBINS_R];
    __shared__ int gbase[NBINS_R];
    __shared__ int lcur[NBINS_R];
    __shared__ int sc[256];
    const int r = blockIdx.y;
    const int* ei = (r == 0) ? ei_ab : (r == 1) ? ei_ba : ei_aa;
    const int t = threadIdx.x;
    for (int i = t; i < NBINS_R; i += 256) lh[i] = 0;
    __syncthreads();
    const int e0 = blockIdx.x * EPB;
    const int e1 = min(e0 + EPB, NEDGE);
    for (int e = e0 + t; e < e1; e += 256)
        atomicAdd(&lh[ei[NEDGE + e] >> BIN_SHIFT], 1);
    __syncthreads();
    {
        const int v = (t < NBINS_R) ? lh[t] : 0;
        sc[t] = v; __syncthreads();
        for (int d = 1; d < 256; d <<= 1) {
            const int x = (t >= d) ? sc[t - d] : 0;
            __syncthreads();
            sc[t] += x;
            __syncthreads();
        }
        if (t < NBINS_R) {
            const int ex = sc[t] - v;
            lbase[t] = ex; lcur[t] = ex;
            gbase[t] = v ? atomicAdd(&bincnt[r * NBINS_R + t], v) : 0;
        }
    }
    __syncthreads();
    for (int e = e0 + t; e < e1; e += 256) {
        const int dst = ei[NEDGE + e];
        const int src = ei[e];
        const int bin = dst >> BIN_SHIFT;
        const int pos = atomicAdd(&lcur[bin], 1);
        sorted[pos] = ((uint_t)(dst & (BIN_W - 1)) << 17) | (uint_t)src;
    }
    __syncthreads();
    const int wid = t >> 6, lane = t & 63;
    for (int b = wid; b < NBINS_R; b += 4) {
        const int cnt = lh[b], lb = lbase[b];
        uint_t* dst = binned + (size_t)(r * NBINS_R + b) * PADBIN + gbase[b];
        for (int k = lane; k < cnt; k += 64) dst[k] = sorted[lb + k];
    }
}

// ---------------- per-bin node offsets + counts + csr fill (one block per bin) ----
__global__ void __launch_bounds__(256)
binfill3_kernel(const uint_t* __restrict__ binned, const int* __restrict__ bincnt,
                int* __restrict__ off3, int* __restrict__ cnt3, int* __restrict__ csr3)
{
    __shared__ int hist[BIN_W];
    __shared__ int A[BIN_W];
    __shared__ int cursor[BIN_W];
    const int b = blockIdx.x;
    const int r = blockIdx.y;
    const int g = r * NBINS_R + b;
    const int start = g * PADBIN;
    const int end = start + bincnt[g];
    const int t = threadIdx.x;
    const int i0 = t, i1 = t + 256;
    hist[i0] = 0; hist[i1] = 0;
    __syncthreads();
    for (int j = start + t; j < end; j += 256)
        atomicAdd(&hist[binned[j] >> 17], 1);
    __syncthreads();
    A[i0] = hist[i0]; A[i1] = hist[i1];
    __syncthreads();
    for (int d = 1; d < BIN_W; d <<= 1) {
        const int x0 = (i0 >= d) ? A[i0 - d] : 0;
        const int x1 = (i1 >= d) ? A[i1 - d] : 0;
        __syncthreads();
        A[i0] += x0; A[i1] += x1;
        __syncthreads();
    }
    const int node0 = b * BIN_W;
#pragma unroll
    for (int q = 0; q < 2; ++q) {
        const int i = t + q * 256;
        const int ex = start + A[i] - hist[i];
        cursor[i] = ex;
        const int node = node0 + i;
        if (node < NA) { off3[r * NA + node] = ex; cnt3[r * NA + node] = hist[i]; }
    }
    __syncthreads();
    for (int j = start + t; j < end; j += 256) {
        const uint_t p = binned[j];
        const int pos = atomicAdd(&cursor[p >> 17], 1);
        csr3[pos] = (int)(p & 0x1FFFFu);
    }
}

// ---------------- gather-aggregate from FP8 tables, half-wave-paired, 8-edge ------
__global__ void __launch_bounds__(256)
gather3_kernel(const uchar_t* __restrict__ h8_a, const uchar_t* __restrict__ h8_b,
               const int* __restrict__ csr3, const int* __restrict__ off3,
               const int* __restrict__ cnt3,
               ushort_t* __restrict__ s_ab, ushort_t* __restrict__ s_ba,
               ushort_t* __restrict__ s_aa)
{
    const int r = blockIdx.y;
    const uchar_t* hsrc = (r == 1) ? h8_b : h8_a;
    ushort_t* s = (r == 0) ? s_ab : (r == 1) ? s_ba : s_aa;
    const int* off = off3 + r * NA;
    const int* cnt = cnt3 + r * NA;
    const int wid = threadIdx.x >> 6, lane = threadIdx.x & 63;
    const int hl = lane & 31;               // half-lane: cols 4*hl .. 4*hl+3
    const int nw = gridDim.x * 4;
    for (int node = blockIdx.x * 4 + wid; node < NA; node += nw) {
        const int o0 = off[node], deg = cnt[node];
        const int o1 = o0 + deg;
        float ax0 = 0.f, ax1 = 0.f, ax2 = 0.f, ax3 = 0.f;
        int j = o0;
        for (; j + 8 <= o1; j += 8) {
            const int s0 = csr3[j],     s1 = csr3[j + 1], s2 = csr3[j + 2], s3 = csr3[j + 3];
            const int s4 = csr3[j + 4], s5 = csr3[j + 5], s6 = csr3[j + 6], s7 = csr3[j + 7];
            const int sA = (lane & 32) ? s1 : s0;
            const int sB = (lane & 32) ? s3 : s2;
            const int sC = (lane & 32) ? s5 : s4;
            const int sD = (lane & 32) ? s7 : s6;
            const uint_t vA = *reinterpret_cast<const uint_t*>(hsrc + (size_t)sA * HD + hl * 4);
            const uint_t vB = *reinterpret_cast<const uint_t*>(hsrc + (size_t)sB * HD + hl * 4);
            const uint_t vC = *reinterpret_cast<const uint_t*>(hsrc + (size_t)sC * HD + hl * 4);
            const uint_t vD = *reinterpret_cast<const uint_t*>(hsrc + (size_t)sD * HD + hl * 4);
            const f32x2 a0 = __builtin_amdgcn_cvt_pk_f32_fp8(vA, false), a1 = __builtin_amdgcn_cvt_pk_f32_fp8(vA, true);
            const f32x2 b0 = __builtin_amdgcn_cvt_pk_f32_fp8(vB, false), b1 = __builtin_amdgcn_cvt_pk_f32_fp8(vB, true);
            const f32x2 c0 = __builtin_amdgcn_cvt_pk_f32_fp8(vC, false), c1 = __builtin_amdgcn_cvt_pk_f32_fp8(vC, true);
            const f32x2 d0 = __builtin_amdgcn_cvt_pk_f32_fp8(vD, false), d1 = __builtin_amdgcn_cvt_pk_f32_fp8(vD, true);
            ax0 += (a0[0] + b0[0]) + (c0[0] + d0[0]);
            ax1 += (a0[1] + b0[1]) + (c0[1] + d0[1]);
            ax2 += (a1[0] + b1[0]) + (c1[0] + d1[0]);
            ax3 += (a1[1] + b1[1]) + (c1[1] + d1[1]);
        }
        for (; j + 2 <= o1; j += 2) {
            const int s0 = csr3[j], s1 = csr3[j + 1];
            const int sA = (lane & 32) ? s1 : s0;
            const uint_t vA = *reinterpret_cast<const uint_t*>(hsrc + (size_t)sA * HD + hl * 4);
            const f32x2 a0 = __builtin_amdgcn_cvt_pk_f32_fp8(vA, false), a1 = __builtin_amdgcn_cvt_pk_f32_fp8(vA, true);
            ax0 += a0[0]; ax1 += a0[1]; ax2 += a1[0]; ax3 += a1[1];
        }
        if (j < o1) {
            const int s0 = csr3[j];
            const uint_t vA = *reinterpret_cast<const uint_t*>(hsrc + (size_t)s0 * HD + hl * 4);
            if (!(lane & 32)) {
                const f32x2 a0 = __builtin_amdgcn_cvt_pk_f32_fp8(vA, false), a1 = __builtin_amdgcn_cvt_pk_f32_fp8(vA, true);
                ax0 += a0[0]; ax1 += a0[1]; ax2 += a1[0]; ax3 += a1[1];
            }
        }
        ax0 += __shfl_xor(ax0, 32); ax1 += __shfl_xor(ax1, 32);
        ax2 += __shfl_xor(ax2, 32); ax3 += __shfl_xor(ax3, 32);
        if (!(lane & 32)) {
            const float inv = 1.0f / fmaxf((float)deg, 1.0f);
            uint2 wv;
            wv.x = pack2bf(ax0 * inv, ax1 * inv);
            wv.y = pack2bf(ax2 * inv, ax3 * inv);
            *reinterpret_cast<uint2*>(s + (size_t)node * HD + hl * 4) = wv;
        }
    }
}

// ---------------- MFMA fused GEMM, no-LDS-W, fragment-major B from global ---------
// C[128 rows x 128 cols] = sum_s X_s @ W_s + bias; relu(opt 0.5*); LDS pool + atomics
template<int NSRC, int SCALE_HALF>
__global__ void __launch_bounds__(256)
mfma_task(const ushort_t* __restrict__ x0, const ushort_t* __restrict__ x1,
          const ushort_t* __restrict__ x2,
          const ushort_t* __restrict__ wtf, const float* __restrict__ bias,
          const int* __restrict__ batch, float* __restrict__ outp, int n)
{
    __shared__ float poolbuf[PG * HD];
    for (int i = threadIdx.x; i < PG * HD; i += 256) poolbuf[i] = 0.f;
    __syncthreads();

    const int l  = threadIdx.x & 63, w = threadIdx.x >> 6;
    const int lo = l & 15, hi = l >> 4;
    const int row_base = blockIdx.x * 128 + w * 32;

    f32x4 acc[2][8];
    const f32x4 zero = {0.f, 0.f, 0.f, 0.f};
#pragma unroll
    for (int mi = 0; mi < 2; ++mi)
#pragma unroll
        for (int ni = 0; ni < 8; ++ni) acc[mi][ni] = zero;

#pragma unroll
    for (int s = 0; s < NSRC; ++s) {
        const ushort_t* xs = (s == 0) ? x0 : (s == 1) ? x1 : x2;
        bf16x8 a[2][4];
#pragma unroll
        for (int mi = 0; mi < 2; ++mi) {
            int r = row_base + mi * 16 + lo;
            r = min(r, n - 1);
            const ushort_t* xr = xs + (size_t)r * HD + hi * 8;
#pragma unroll
            for (int kk = 0; kk < 4; ++kk)
                a[mi][kk] = *reinterpret_cast<const bf16x8*>(xr + kk * 32);
        }
        const ushort_t* wm = wtf + (size_t)s * 16384;
#pragma unroll
        for (int kk = 0; kk < 4; ++kk) {
#pragma unroll
            for (int ni = 0; ni < 8; ++ni) {
                const bf16x8 b = *reinterpret_cast<const bf16x8*>(wm + ((size_t)(kk * 8 + ni) * 64 + l) * 8);
                acc[0][ni] = __builtin_amdgcn_mfma_f32_16x16x32_bf16(a[0][kk], b, acc[0][ni], 0, 0, 0);
                acc[1][ni] = __builtin_amdgcn_mfma_f32_16x16x32_bf16(a[1][kk], b, acc[1][ni], 0, 0, 0);
            }
        }
    }

    const int gmin = batch[blockIdx.x * 128];
    int gg[2][4];
#pragma unroll
    for (int mi = 0; mi < 2; ++mi)
#pragma unroll
        for (int r = 0; r < 4; ++r) {
            const int row = row_base + mi * 16 + hi * 4 + r;
            gg[mi][r] = (row < n) ? batch[row] : -1;
        }

#pragma unroll
    for (int ni = 0; ni < 8; ++ni) {
        const int col = ni * 16 + lo;
        const float bv = bias[col];
#pragma unroll
        for (int mi = 0; mi < 2; ++mi) {
            const f32x4 v = acc[mi][ni];
#pragma unroll
            for (int r = 0; r < 4; ++r) {
                const int g = gg[mi][r];
                if (g >= 0) {
                    float val = v[r] + bv;
                    if (SCALE_HALF) val *= 0.5f;
                    val = fmaxf(val, 0.f);
                    const unsigned slot = (unsigned)(g - gmin);
                    if (slot < PG) atomicAdd(&poolbuf[slot * HD + col], val);
                    else unsafeAtomicAdd(outp + (size_t)g * HD + col, val);
                }
            }
        }
    }
    __syncthreads();
    for (int i = threadIdx.x; i < PG * HD; i += 256) {
        const float v = poolbuf[i];
        if (v != 0.f) {
            const int g = gmin + (i >> 7);
            if (g < NG) unsafeAtomicAdd(outp + (size_t)g * HD + (i & 127), v);
        }
    }
}

// ---------------- head: out = (0.5*(pa/ga + pb/gb)) @ Wout + bout ----------------
__global__ void final_kernel(const float* __restrict__ pa, const float* __restrict__ pb,
                             const float* __restrict__ ga, const float* __restrict__ gb,
                             const float* __restrict__ Wout, const float* __restrict__ bout,
                             float* __restrict__ out)
{
    const int g = blockIdx.x;
    const int lane = threadIdx.x;
    const float inva = 1.0f / fmaxf(ga[g], 1.0f);
    const float invb = 1.0f / fmaxf(gb[g], 1.0f);
    if (lane < OUTD) {
        float acc = bout[lane];
        for (int k = 0; k < HD; ++k) {
            const float x = 0.5f * (pa[g * HD + k] * inva + pb[g * HD + k] * invb);
            acc = fmaf(x, Wout[k * OUTD + lane], acc);
        }
        out[g * OUTD + lane] = acc;
    }
}

extern "C" void kernel_launch(void* const* d_in, const int* in_sizes, int n_in,
                              void* d_out, int out_size, void* d_ws, size_t ws_size,
                              hipStream_t stream)
{
    const float* x_a     = (const float*)d_in[0];
    const float* x_b     = (const float*)d_in[1];
    const int*   ei_ab   = (const int*)d_in[2];
    const int*   ei_ba   = (const int*)d_in[3];
    const int*   ei_aa   = (const int*)d_in[4];
    const int*   batch_a = (const int*)d_in[5];
    const int*   batch_b = (const int*)d_in[6];
    const float* Wemb_a  = (const float*)d_in[7];
    const float* bemb_a  = (const float*)d_in[8];
    const float* Wemb_b  = (const float*)d_in[9];
    const float* bemb_b  = (const float*)d_in[10];
    const float* Wl_ab   = (const float*)d_in[11];
    const float* bl_ab   = (const float*)d_in[12];
    const float* Wr_ab   = (const float*)d_in[13];
    const float* Wl_ba   = (const float*)d_in[14];
    const float* bl_ba   = (const float*)d_in[15];
    const float* Wr_ba   = (const float*)d_in[16];
    const float* Wl_aa   = (const float*)d_in[17];
    const float* bl_aa   = (const float*)d_in[18];
    const float* Wr_aa   = (const float*)d_in[19];
    const float* Wout    = (const float*)d_in[20];
    const float* bout    = (const float*)d_in[21];
    float* out = (float*)d_out;

    // ---------------- workspace layout ----------------
    char* p = (char*)d_ws;
    ushort_t* h_a  = (ushort_t*)p; p += (size_t)NA * HD * 2;     // h_a, h_b contiguous
    ushort_t* h_b  = (ushort_t*)p; p += (size_t)NB * HD * 2;
    ushort_t* s_ab = (ushort_t*)p; p += (size_t)NB * HD * 2;
    ushort_t* s_ba = (ushort_t*)p; p += (size_t)NA * HD * 2;
    ushort_t* s_aa = (ushort_t*)p; p += (size_t)NA * HD * 2;
    uchar_t* h8_a  = (uchar_t*)p;  p += (size_t)NA * HD;         // h8_a, h8_b contiguous
    uchar_t* h8_b  = (uchar_t*)p;  p += (size_t)NB * HD;
    int* csr3   = (int*)p;  p += (size_t)NBINS * PADBIN * 4;     // 24.1 MB (padded)
    uint_t* binned = (uint_t*)p; p += (size_t)NBINS * PADBIN * 4;// 24.1 MB (padded)
    int* off3   = (int*)p;  p += (size_t)3 * NA * 4;
    int* cnt3   = (int*)p;  p += (size_t)3 * NA * 4;
    int* bincnt = (int*)p;  p += (NBINS + 4) * 4;
    float* pool_a = (float*)p; p += (size_t)NG * HD * 4;
    float* pool_b = (float*)p; p += (size_t)NG * HD * 4;
    float* gcnt_a = (float*)p; p += NG * 4;
    float* gcnt_b = (float*)p; p += NG * 4;
    ushort_t* wt_fb = (ushort_t*)p; p += 2 * 16384 * 2;
    ushort_t* wt_pa = (ushort_t*)p; p += 3 * 16384 * 2;
    ushort_t* wt_ea = (ushort_t*)p; p += 64 * HD * 2;
    ushort_t* wt_eb = (ushort_t*)p; p += 32 * HD * 2;
    float* bias_pa  = (float*)p;    p += HD * 4;

    const int GT = (NA + 127) / 128;                           // 782

    hipMemsetAsync(pool_a, 0, (size_t)2 * NG * HD * 4, stream);
    hipMemsetAsync(bincnt, 0, (size_t)NBINS * 4, stream);

    prep_misc_kernel<<<49, 256, 0, stream>>>(Wl_ab, Wr_ab, Wl_ba, Wl_aa, Wr_ba, Wr_aa,
                                             Wemb_a, Wemb_b, wt_fb, wt_pa, wt_ea, wt_eb,
                                             bl_ba, bl_aa, bias_pa,
                                             batch_a, batch_b, gcnt_a, gcnt_b);

    emb_mfma<DA><<<GT, 256, 0, stream>>>(x_a, wt_ea, bemb_a, h_a, NA);
    emb_mfma<DB><<<GT, 256, 0, stream>>>(x_b, wt_eb, bemb_b, h_b, NB);
    conv8_kernel<<<2048, 256, 0, stream>>>(h_a, h8_a, (long)(NA + NB) * HD / 8);

    // ---- padded-bin CSR build ----
    part3_kernel<<<dim3(ECHUNKS, 3), 256, 0, stream>>>(ei_ab, ei_ba, ei_aa, bincnt, binned);
    binfill3_kernel<<<dim3(NBINS_R, 3), 256, 0, stream>>>(binned, bincnt, off3, cnt3, csr3);

    gather3_kernel<<<dim3(2048, 3), 256, 0, stream>>>(h8_a, h8_b, csr3, off3, cnt3, s_ab, s_ba, s_aa);

    // ---- MFMA fused GEMMs: no-LDS-W, B fragments streamed from L2 ----
    // dst 'b': relu(s_ab@Wl_ab + h_b@Wr_ab + bl_ab) -> pool_b
    mfma_task<2, 0><<<GT, 256, 0, stream>>>(s_ab, h_b, nullptr, wt_fb, bl_ab, batch_b, pool_b, NB);
    // dst 'a': relu(0.5*(s_ba@Wl_ba + s_aa@Wl_aa + h_a@(Wr_ba+Wr_aa) + bl_ba+bl_aa)) -> pool_a
    mfma_task<3, 1><<<GT, 256, 0, stream>>>(s_ba, s_aa, h_a, wt_pa, bias_pa, batch_a, pool_a, NA);

    final_kernel<<<NG, 64, 0, stream>>>(pool_a, pool_b, gcnt_a, gcnt_b, Wout, bout, out);
}